// Round 11
// baseline (277.567 us; speedup 1.0000x reference)
//
#include <hip/hip_runtime.h>
#include <hip/hip_bf16.h>

// Problem constants
#define Bb 4
#define Ls 1024
#define Dd 1024
#define Nn 16
#define Hh 64
#define Rr 2048

typedef __attribute__((ext_vector_type(8))) short short8;
typedef __attribute__((ext_vector_type(4))) short short4v;
typedef __attribute__((ext_vector_type(4))) float f32x4;

__device__ __forceinline__ float bf2f(short s) {
    union { unsigned u; float f; } c;
    c.u = ((unsigned)(unsigned short)s) << 16;
    return c.f;
}
__device__ __forceinline__ short f2bf(float f) {
    __hip_bfloat16 h = __float2bfloat16(f);
    return *reinterpret_cast<short*>(&h);
}

// async global->LDS, 16B per lane; LDS dest = wave-uniform base + lane*16
__device__ __forceinline__ void gld16(const void* g, void* l) {
    __builtin_amdgcn_global_load_lds(
        (const __attribute__((address_space(1))) unsigned int*)g,
        (__attribute__((address_space(3))) unsigned int*)l, 16, 0, 0);
}

// ---------------------------------------------------------------------------
// Prep (merged): f32->bf16 convert-copies AND all weight transposes in ONE
// dispatch (see r8 notes).
// ---------------------------------------------------------------------------
struct CopyDesc {
    const float* src[4];
    short* dst[4];
    int n[4];
};
struct TransDesc {
    const float* src[4];
    short* dst[4];
};

__global__ __launch_bounds__(256) void prep_all(
    CopyDesc cd, TransDesc td, const float* __restrict__ rker,
    short* __restrict__ rkT)
{
    const int bid = (int)blockIdx.x;
    const int t   = threadIdx.x;

    if (bid < 8192) {
        // ---- convert-copy path ----
        const int z = bid >> 11;
        const int base = ((bid & 2047) * 256 + t) * 8;
        if (base >= cd.n[z]) return;
        const float* s = cd.src[z] + base;
        const float4 a = *(const float4*)s;
        const float4 b = *(const float4*)(s + 4);
        short8 o;
        o[0] = f2bf(a.x); o[1] = f2bf(a.y); o[2] = f2bf(a.z); o[3] = f2bf(a.w);
        o[4] = f2bf(b.x); o[5] = f2bf(b.y); o[6] = f2bf(b.z); o[7] = f2bf(b.w);
        *(short8*)(cd.dst[z] + base) = o;
        return;
    }

    // ---- transpose path ----
    const int tw = bid - 8192;
    const float* in; short* out; int C, r0, c0;
    if (tw < 1024) {
        const int z = tw >> 8, rem = tw & 255;
        in = td.src[z]; out = td.dst[z]; C = 1024;
        r0 = ((rem >> 4) & 15) * 64; c0 = (rem & 15) * 64;
    } else {
        const int s2 = tw - 1024;
        const int sl = s2 >> 4, y = s2 & 15;
        in  = rker + (long)sl * 1024 * 64;
        out = rkT  + (long)sl * 64 * 1024;
        C = 64; r0 = y * 64; c0 = 0;
    }
    __shared__ float T[64][65];
    const int rr = t >> 4, c4 = (t & 15) * 4;
#pragma unroll
    for (int p = 0; p < 4; ++p) {
        const float4 v = *(const float4*)&in[(long)(r0 + p * 16 + rr) * C + c0 + c4];
        T[p * 16 + rr][c4 + 0] = v.x;
        T[p * 16 + rr][c4 + 1] = v.y;
        T[p * 16 + rr][c4 + 2] = v.z;
        T[p * 16 + rr][c4 + 3] = v.w;
    }
    __syncthreads();
#pragma unroll
    for (int p = 0; p < 4; ++p) {
        const int j = p * 16 + (t >> 4);
        const int d4 = (t & 15) * 4;
        short4v o;
#pragma unroll
        for (int u = 0; u < 4; ++u) o[u] = f2bf(T[d4 + u][j]);
        *(short4v*)&out[(long)(c0 + j) * 1024 + r0 + d4] = o;
    }
}

// ---------------------------------------------------------------------------
// MFMA GEMM (r9): BK=64 + XOR-swizzled LDS + counted vmcnt 2-phase.
// (unchanged this round — see r9 notes)
// ---------------------------------------------------------------------------
__global__ __launch_bounds__(256) void gemm_bt(
    const short* __restrict__ A, int lda, long aStride,
    const short* __restrict__ Bt, int ldb, long bStride,
    const float* __restrict__ bias,
    const float* __restrict__ kb, const float* __restrict__ vb,
    const float* __restrict__ residual, int ldr,
    void* __restrict__ Cv, int ldc, long cStride, int out_bf16, int K, int zsplit)
{
    const int bid   = (int)blockIdx.x;
    const int chunk = (int)gridDim.x >> 3;
    const int work  = (bid & 7) * chunk + (bid >> 3);
    int z, r;
    if (work < zsplit) { z = work >> 8; r = work & 255; }
    else               { z = 3;         r = work - zsplit; }
    const int by = r >> 3;
    const int bx = r & 7;

    A  += (long)z * aStride;
    Bt += (long)z * bStride;

    const int row0 = by * 128;
    const int col0 = bx * 128;

    __shared__ short As[2][128 * 64];
    __shared__ short Bs[2][128 * 64];

    const int tid  = threadIdx.x;
    const int w    = tid >> 6;
    const int lane = tid & 63;
    const int quad = lane >> 4;
    const int ln16 = lane & 15;
    const int wr   = (w >> 1) * 64;
    const int wc   = (w & 1) * 64;

    f32x4 acc[4][4];
#pragma unroll
    for (int a = 0; a < 4; ++a)
#pragma unroll
        for (int b = 0; b < 4; ++b) acc[a][b] = (f32x4){0.f, 0.f, 0.f, 0.f};

    // staging lane constants (XOR swizzle, attn ks pattern)
    const int srow8 = lane >> 3;            // row within 8-row chunk
    const int sunit = (lane & 7) ^ srow8;   // inverse-swizzled source 16B unit
    const int swz   = ln16 & 7;             // read-side swizzle factor

    // ---- prologue: stage tile 0 (8 gld16/wave: 4 A-chunks + 4 B-chunks) ----
#pragma unroll
    for (int j = 0; j < 4; ++j) {
        const int c = w * 4 + j;            // chunk 0..15 (8 rows each)
        gld16(A  + (long)(row0 + c * 8 + srow8) * lda + sunit * 8,
              As[0] + c * 512);
        gld16(Bt + (long)(col0 + c * 8 + srow8) * ldb + sunit * 8,
              Bs[0] + c * 512);
    }

    int cur = 0;
    for (int k0 = 0; k0 < K; k0 += 64) {
        __builtin_amdgcn_s_barrier();       // A: nxt buffer free (all waves)

        if (k0 + 64 < K) {
            const int nxt = cur ^ 1;
#pragma unroll
            for (int j = 0; j < 4; ++j) {
                const int c = w * 4 + j;
                gld16(A  + (long)(row0 + c * 8 + srow8) * lda + k0 + 64 + sunit * 8,
                      As[nxt] + c * 512);
                gld16(Bt + (long)(col0 + c * 8 + srow8) * ldb + k0 + 64 + sunit * 8,
                      Bs[nxt] + c * 512);
            }
            asm volatile("s_waitcnt vmcnt(8)" ::: "memory");   // tile k landed
        } else {
            asm volatile("s_waitcnt vmcnt(0)" ::: "memory");   // last tile
        }
        __builtin_amdgcn_s_barrier();       // B: every wave's tile-k data in LDS
        __builtin_amdgcn_sched_barrier(0);

        // ---- compute current tile (next tile's loads still in flight) ----
        short8 af[4][2], bfr[4][2];
#pragma unroll
        for (int tm = 0; tm < 4; ++tm) {
            const int row = wr + tm * 16 + ln16;
#pragma unroll
            for (int kk = 0; kk < 2; ++kk) {
                const int unit = (kk * 4 + quad) ^ swz;
                af[tm][kk] = *(const short8*)&As[cur][row * 64 + unit * 8];
            }
        }
#pragma unroll
        for (int tn = 0; tn < 4; ++tn) {
            const int row = wc + tn * 16 + ln16;
#pragma unroll
            for (int kk = 0; kk < 2; ++kk) {
                const int unit = (kk * 4 + quad) ^ swz;
                bfr[tn][kk] = *(const short8*)&Bs[cur][row * 64 + unit * 8];
            }
        }
#pragma unroll
        for (int tm = 0; tm < 4; ++tm)
#pragma unroll
            for (int tn = 0; tn < 4; ++tn) {
                acc[tm][tn] = __builtin_amdgcn_mfma_f32_16x16x32_bf16(
                    af[tm][0], bfr[tn][0], acc[tm][tn], 0, 0, 0);
                acc[tm][tn] = __builtin_amdgcn_mfma_f32_16x16x32_bf16(
                    af[tm][1], bfr[tn][1], acc[tm][tn], 0, 0, 0);
            }

        cur ^= 1;
    }

    const float* bz = bias;
    if (z == 1) bz = kb;
    else if (z == 2) bz = vb;

    float bv[4];
#pragma unroll
    for (int tn = 0; tn < 4; ++tn)
        bv[tn] = bz ? bz[col0 + wc + tn * 16 + ln16] : 0.f;

    short* Cb = (short*)Cv + (long)z * cStride;
    float* Cf = (float*)Cv + (long)z * cStride;
#pragma unroll
    for (int tm = 0; tm < 4; ++tm) {
#pragma unroll
        for (int r2 = 0; r2 < 4; ++r2) {
            const long row = row0 + wr + tm * 16 + quad * 4 + r2;
#pragma unroll
            for (int tn = 0; tn < 4; ++tn) {
                const int col = col0 + wc + tn * 16 + ln16;
                float val = acc[tm][tn][r2] + bv[tn];
                if (residual) val += residual[row * (long)ldr + col];
                if (out_bf16) Cb[row * (long)ldc + col] = f2bf(val);
                else          Cf[row * (long)ldc + col] = val;
            }
        }
    }
}

// ---------------------------------------------------------------------------
// MFMA attention (r10): ASYNC pipeline — per-iteration prefetch of the NEXT
// tile's K/ring/V with the loads kept in flight across the compute phase.
//   bar A = __syncthreads(): drains LAST iteration's loads (they had a full
//     compute phase to land -> near-free) and frees vsT / ks[nxt] / ring tail.
//   V^T store from regs, THEN issue mt+1 prefetches (K->ks[cur^1], ring tail,
//     V regs), lgkmcnt(0) for vsT cross-wave visibility, RAW s_barrier (does
//     NOT drain vmcnt -> the 6 new loads stay in flight), compute.
// ks double-buffered (+8KB). LDS 75.1 KB -> 2 blocks/CU.
// Everything else as r8/r9 (ring rS, kf/vf hoist, kc-packed P, ballot mask,
// fixed-max softmax, XCD swizzle).
// ---------------------------------------------------------------------------
#define SCALE_L2E 0.18033688f      // 0.125 * log2(e)

__global__ __launch_bounds__(256, 2) void attn_mfma(
    const short* __restrict__ qh, const short* __restrict__ kh,
    const short* __restrict__ vh, const short* __restrict__ rS,
    const int* __restrict__ padding, const float* __restrict__ rwb,
    const float* __restrict__ rrb, short* __restrict__ ao)
{
    // ---- XCD-aware decode: work = b*128 + n*8 + lt (chunk = 64) ----
    const int bid   = (int)blockIdx.x;
    const int chunk = (int)gridDim.x >> 3;      // 64
    const int work  = (bid & 7) * chunk + (bid >> 3);
    const int lt = work & 7;
    const int n  = (work >> 3) & 15;
    const int b  = work >> 7;

    const int l0 = lt * 128;
    const int tid  = threadIdx.x;
    const int w    = tid >> 6;
    const int lane = tid & 63;
    const int quad = lane >> 4;
    const int ln16 = lane & 15;
    const int qb   = w * 32;          // wave's query base within block

    __shared__ __align__(16) short ks[2][64 * 64]; // DBUF, XOR-swizzled
    __shared__ __align__(16) short rsb[256 * 64];  // RING, XOR-swizzled
    __shared__ __align__(16) short vsT[64][72];    // [d][kc] permuted keys
    __shared__ __align__(16) short psm[4][2][16][72];
    __shared__ unsigned padw[32];                  // pad bitmask, 1024 bits

    // ---- build pad bitmask via wave ballot (16 groups of 64 keys) ----
#pragma unroll
    for (int j = 0; j < 4; ++j) {
        const int g = w + 4 * j;                    // 0..15
        const unsigned long long m =
            __ballot(padding[b * Ls + g * 64 + lane] != 0);
        if (lane == 0) {
            padw[2 * g]     = (unsigned)m;
            padw[2 * g + 1] = (unsigned)(m >> 32);
        }
    }

    // Q fragments (A-layout) for both Q-tiles, biased two ways
    short8 qwf[2][2], qrf[2][2];
#pragma unroll
    for (int qt = 0; qt < 2; ++qt) {
        const long rowoff =
            ((long)(b * Ls + l0 + qb + qt * 16 + ln16)) * (Nn * Hh) + n * Hh;
#pragma unroll
        for (int c = 0; c < 2; ++c) {
            const int kb2 = c * 32 + quad * 8;
            short8 qv = *(const short8*)(qh + rowoff + kb2);
#pragma unroll
            for (int j = 0; j < 8; ++j) {
                float qf = bf2f(qv[j]);
                qwf[qt][c][j] = f2bf(qf + rwb[n * Hh + kb2 + j]);
                qrf[qt][c][j] = f2bf(qf + rrb[n * Hh + kb2 + j]);
            }
        }
    }

    float lsum[2][4];
    f32x4 accO[2][4];
#pragma unroll
    for (int qt = 0; qt < 2; ++qt)
#pragma unroll
        for (int r = 0; r < 4; ++r) {
            lsum[qt][r] = 0.f;
            accO[qt][r] = (f32x4){0.f, 0.f, 0.f, 0.f};
        }

    // staging lane constants (global_load_lds: LDS dest = base + lane*16)
    const int srow8 = lane >> 3;            // row within 8-row chunk
    const int sunit = (lane & 7) ^ srow8;   // inverse-swizzled source 16B unit
    const int swz   = ln16 & 7;             // read-side swizzle factor

    // ---- prologue: K tile 0 -> ks[0]; ring rows [897-l0, +192) ----
#pragma unroll
    for (int j = 0; j < 2; ++j) {
        const int c = w * 2 + j;
        gld16(kh + ((long)(b * Ls + c * 8 + srow8)) * 1024 + n * 64 + sunit * 8,
              ks[0] + c * 512);
    }
    {
        const int base0 = 897 - l0;          // >= 1; max row 1088 (no clamp)
#pragma unroll
        for (int j = 0; j < 6; ++j) {
            const int c = w * 6 + j;         // 0..23
            const int rg = base0 + c * 8 + srow8;
            gld16(rS + (long)rg * 1024 + n * 64 + sunit * 8,
                  rsb + c * 512);
        }
    }

    // V prefetch: thread handles key pair (kp2, kp2+16) -> contiguous kc pair
    const int s5  = tid & 31;
    const int kp2 = (s5 & 15) + ((s5 >> 4) << 5);     // 0..15 or 32..47
    const int kcb = 4 * (s5 & 15) + 2 * (s5 >> 4);    // kc of kp2 (kc+1 = kp2+16)
    const int cq  = (tid >> 5) * 8;                   // d-group base
    short8 va, vb2;
    {
        const short* vp = vh + ((long)(b * Ls + kp2)) * 1024 + n * 64 + cq;
        va  = *(const short8*)vp;
        vb2 = *(const short8*)(vp + 16 * 1024);
    }

    int cur = 0;
    for (int mt = 0; mt < Ls / 64; ++mt) {
        const int m0 = mt * 64;
        // bar A: drains last iteration's loads (landed during compute) and
        // frees vsT / ks[cur^1] / ring tail chunks for overwrite.
        __syncthreads();

        // ---- V^T store from prefetched regs, kc-permuted key pairs ----
#pragma unroll
        for (int u = 0; u < 8; ++u) {
            unsigned pk = ((unsigned)(unsigned short)va[u]) |
                          (((unsigned)(unsigned short)vb2[u]) << 16);
            *(unsigned*)&vsT[cq + u][kcb] = pk;
        }

        // ---- issue mt+1 prefetches (in flight across compute) ----
        {
            const int m1 = m0 + 64;
            const int nxt = cur ^ 1;
            // K tile mt+1 (last iter overruns into adjacent ws; never read)
#pragma unroll
            for (int j = 0; j < 2; ++j) {
                const int c = w * 2 + j;
                gld16(kh + ((long)(b * Ls + m1 + c * 8 + srow8)) * 1024
                         + n * 64 + sunit * 8,
                      ks[nxt] + c * 512);
            }
            // ring tail for window mt+1
            const int tail = 1089 + m0 - l0;            // base(mt) + 192
            const int rcB  = (24 + 8 * mt) & 31;
#pragma unroll
            for (int j = 0; j < 2; ++j) {
                const int jl = w * 2 + j;               // 0..7
                const int rc = (rcB + jl) & 31;         // ring chunk
                int rg = tail + jl * 8 + srow8;
                rg = rg < 2047 ? rg : 2047;             // clamped never gathered
                gld16(rS + (long)rg * 1024 + n * 64 + sunit * 8,
                      rsb + rc * 512);
            }
            // V regs for mt+1 (wraps at end; harmless)
            const int mn = m1 & (Ls - 1);
            const short* vp = vh + ((long)(b * Ls + mn + kp2)) * 1024 + n * 64 + cq;
            va  = *(const short8*)vp;
            vb2 = *(const short8*)(vp + 16 * 1024);
        }

        // vsT ds_writes drained (per-wave), then raw barrier: cross-wave
        // visibility WITHOUT draining the just-issued vmcnt loads.
        asm volatile("s_waitcnt lgkmcnt(0)" ::: "memory");
        __builtin_amdgcn_s_barrier();
        __builtin_amdgcn_sched_barrier(0);

        // ---- Pr B-fragments: 6 union tiles from the ring (shared by qt) ----
        const int rb0 = (96 - qb) + ln16 + m0;   // ring row before &255
        short8 rfU[6][2];
#pragma unroll
        for (int s = 0; s < 6; ++s) {
            const int rr2 = (rb0 + s * 16) & 255;
#pragma unroll
            for (int c2 = 0; c2 < 2; ++c2) {
                const int unit = (c2 * 4 + quad) ^ swz;
                rfU[s][c2] = *(const short8*)&rsb[rr2 * 64 + unit * 8];
            }
        }

        // ---- S = Q K^T (kf hoisted across qt) ----
        __builtin_amdgcn_s_setprio(1);
        f32x4 Sf[2][4];
#pragma unroll
        for (int t = 0; t < 4; ++t) {
            short8 kf0, kf1;
            {
                const int u0 = (0 * 4 + quad) ^ swz;
                const int u1 = (1 * 4 + quad) ^ swz;
                kf0 = *(const short8*)&ks[cur][(t * 16 + ln16) * 64 + u0 * 8];
                kf1 = *(const short8*)&ks[cur][(t * 16 + ln16) * 64 + u1 * 8];
            }
#pragma unroll
            for (int qt = 0; qt < 2; ++qt) {
                f32x4 c = (f32x4){0.f, 0.f, 0.f, 0.f};
                c = __builtin_amdgcn_mfma_f32_16x16x32_bf16(qwf[qt][0], kf0, c, 0, 0, 0);
                c = __builtin_amdgcn_mfma_f32_16x16x32_bf16(qwf[qt][1], kf1, c, 0, 0, 0);
                Sf[qt][t] = c;
            }
        }
        // ---- Pr = Qr · band^T : 5 col-tiles per qt (rfU shared) ----
        f32x4 Prf[2][5];
#pragma unroll
        for (int t = 0; t < 5; ++t) {
#pragma unroll
            for (int qt = 0; qt < 2; ++qt) {
                const int off = qt ? 0 : 1;     // Qt0 -> tiles 1..5, Qt1 -> 0..4
                f32x4 c = (f32x4){0.f, 0.f, 0.f, 0.f};
                c = __builtin_amdgcn_mfma_f32_16x16x32_bf16(qrf[qt][0], rfU[t + off][0], c, 0, 0, 0);
                c = __builtin_amdgcn_mfma_f32_16x16x32_bf16(qrf[qt][1], rfU[t + off][1], c, 0, 0, 0);
                Prf[qt][t] = c;
            }
        }
        __builtin_amdgcn_s_setprio(0);

        // ---- skew gather + fixed-max exp; P stored kc-packed (b64) ----
        const unsigned w0 = padw[(m0 >> 5)];
        const unsigned w1 = padw[(m0 >> 5) + 1];
        const float mbc = -16.0f * 1.44269504f;
        const float mb0 = ((w0 >> ln16) & 1)        ? -1.0e7f : mbc;
        const float mb1 = ((w0 >> (16 + ln16)) & 1) ? -1.0e7f : mbc;
        const float mb2 = ((w1 >> ln16) & 1)        ? -1.0e7f : mbc;
        const float mb3 = ((w1 >> (16 + ln16)) & 1) ? -1.0e7f : mbc;
#pragma unroll
        for (int qt = 0; qt < 2; ++qt) {
#pragma unroll
            for (int r = 0; r < 4; ++r) {
                const int row = quad * 4 + r;
                const int u = ln16 - row + 15;
                const int srcLane = (quad << 4) | (u & 15);
                const float s0 = __shfl(Prf[qt][0][r], srcLane, 64);
                const float s1 = __shfl(Prf[qt][1][r], srcLane, 64);
                const float s2 = __shfl(Prf[qt][2][r], srcLane, 64);
                const float s3 = __shfl(Prf[qt][3][r], srcLane, 64);
                const float s4 = __shfl(Prf[qt][4][r], srcLane, 64);
                const bool hi = (u >= 16);
                const float p0 = __builtin_amdgcn_exp2f(
                    fmaf(Sf[qt][0][r] + (hi ? s1 : s0), SCALE_L2E, mb0));
                const float p1 = __builtin_amdgcn_exp2f(
                    fmaf(Sf[qt][1][r] + (hi ? s2 : s1), SCALE_L2E, mb1));
                const float p2 = __builtin_amdgcn_exp2f(
                    fmaf(Sf[qt][2][r] + (hi ? s3 : s2), SCALE_L2E, mb2));
                const float p3 = __builtin_amdgcn_exp2f(
                    fmaf(Sf[qt][3][r] + (hi ? s4 : s3), SCALE_L2E, mb3));
                lsum[qt][r] += (p0 + p1) + (p2 + p3);
                short4v pk;
                pk[0] = f2bf(p0); pk[1] = f2bf(p1);
                pk[2] = f2bf(p2); pk[3] = f2bf(p3);
                *(short4v*)&psm[w][qt][row][ln16 * 4] = pk;   // kc = ln16*4 + t
            }
        }

        // ---- PV : merged across qt, vf read once per t ----
        short8 pA[2][2];
#pragma unroll
        for (int qt = 0; qt < 2; ++qt)
#pragma unroll
            for (int c2 = 0; c2 < 2; ++c2)
                pA[qt][c2] = *(short8*)&psm[w][qt][ln16][c2 * 32 + quad * 8];
        __builtin_amdgcn_s_setprio(1);
#pragma unroll
        for (int t = 0; t < 4; ++t) {
            short8 vf0 = *(short8*)&vsT[t * 16 + ln16][quad * 8];
            short8 vf1 = *(short8*)&vsT[t * 16 + ln16][32 + quad * 8];
#pragma unroll
            for (int qt = 0; qt < 2; ++qt) {
                f32x4 c = accO[qt][t];
                c = __builtin_amdgcn_mfma_f32_16x16x32_bf16(pA[qt][0], vf0, c, 0, 0, 0);
                c = __builtin_amdgcn_mfma_f32_16x16x32_bf16(pA[qt][1], vf1, c, 0, 0, 0);
                accO[qt][t] = c;
            }
        }
        __builtin_amdgcn_s_setprio(0);

        cur ^= 1;
    }

    // ---- final l reduction (once), then normalize + coalesced store ----
#pragma unroll
    for (int qt = 0; qt < 2; ++qt) {
#pragma unroll
        for (int r = 0; r < 4; ++r) {
            float v = lsum[qt][r];
#pragma unroll
            for (int of = 1; of < 16; of <<= 1) v += __shfl_xor(v, of, 64);
            lsum[qt][r] = 1.f / v;
        }
#pragma unroll
        for (int t = 0; t < 4; ++t)
#pragma unroll
            for (int r = 0; r < 4; ++r)
                psm[w][qt][quad * 4 + r][t * 16 + ln16] =
                    f2bf(accO[qt][t][r] * lsum[qt][(unsigned)r]);
#pragma unroll
        for (int p = 0; p < 2; ++p) {
            const int c = lane + p * 64;
            const int row = c >> 3, cq2 = (c & 7) * 8;
            const long grow = (long)(b * Ls + l0 + qb + qt * 16 + row);
            *(short8*)(ao + grow * 1024 + n * 64 + cq2) = *(short8*)&psm[w][qt][row][cq2];
        }
    }
}

// ---------------------------------------------------------------------------
// LayerNorm in-place over rows of x (4096 x 1024)
// ---------------------------------------------------------------------------
__global__ __launch_bounds__(256) void ln_kernel(
    float* x, const float* __restrict__ g, const float* __restrict__ bb)
{
    const int row = blockIdx.x;
    const int tid = threadIdx.x;
    float4 v = ((const float4*)(x + (long)row * Dd))[tid];
    float s  = v.x + v.y + v.z + v.w;
    float sq = v.x * v.x + v.y * v.y + v.z * v.z + v.w * v.w;
#pragma unroll
    for (int off = 32; off; off >>= 1) {
        s  += __shfl_down(s, off, 64);
        sq += __shfl_down(sq, off, 64);
    }
    __shared__ float ws_s[4], ws_q[4];
    __shared__ float s_mu, s_rstd;
    const int wave = tid >> 6, lane = tid & 63;
    if (lane == 0) { ws_s[wave] = s; ws_q[wave] = sq; }
    __syncthreads();
    if (tid == 0) {
        const float ts = ws_s[0] + ws_s[1] + ws_s[2] + ws_s[3];
        const float tq = ws_q[0] + ws_q[1] + ws_q[2] + ws_q[3];
        const float mu = ts / (float)Dd;
        const float var = tq / (float)Dd - mu * mu;
        s_mu = mu;
        s_rstd = rsqrtf(var + 1e-5f);
    }
    __syncthreads();
    const float mu = s_mu, rstd = s_rstd;
    const float4 gv = ((const float4*)g)[tid];
    const float4 bv = ((const float4*)bb)[tid];
    float4 o;
    o.x = (v.x - mu) * rstd * gv.x + bv.x;
    o.y = (v.y - mu) * rstd * gv.y + bv.y;
    o.z = (v.z - mu) * rstd * gv.z + bv.z;
    o.w = (v.w - mu) * rstd * gv.w + bv.w;
    ((float4*)(x + (long)row * Dd))[tid] = o;
}

// ---------------------------------------------------------------------------
extern "C" void kernel_launch(void* const* d_in, const int* in_sizes, int n_in,
                              void* d_out, int out_size, void* d_ws, size_t ws_size,
                              hipStream_t stream) {
    const float* q      = (const float*)d_in[0];
    const float* k      = (const float*)d_in[1];
    const float* v      = (const float*)d_in[2];
    const float* posenc = (const float*)d_in[3];
    const int*   pad    = (const int*)  d_in[4];
    const float* q_w    = (const float*)d_in[5];
    const float* k_w    = (const float*)d_in[6];
    const float* k_b    = (const float*)d_in[7];
    const float* v_w    = (const float*)d_in[8];
    const float* v_b    = (const float*)d_in[9];
    const float* rwb    = (const float*)d_in[10];
    const float* rrb    = (const float*)d_in[11];
    const float* r_ker  = (const float*)d_in[12];
    const float* post_w = (const float*)d_in[13];
    const float* post_b = (const float*)d_in[14];
    const float* ln_g   = (const float*)d_in[15];
    const float* ln_b   = (const float*)d_in[16];
    float* out = (float*)d_out;

    const long M1 = 1L << 20;                 // 1M elements
    short* ws = (short*)d_ws;
    short* xq   = ws;                         // 4M (z=0 A; aliased by ao later)
    short* xk   = ws + 4 * M1;                // 4M (z=1 A)
    short* xv   = ws + 8 * M1;                // 4M (z=2 A)
    short* pe   = ws + 12 * M1;               // 2M (z=3 A)  == xq + 3*4M
    short* wT   = ws + 14 * M1;               // 3M (qwT,kwT,vwT = z=0..2 B)
    short* rkT  = ws + 17 * M1;               // 1M (z=3 B)  == wT + 3*1M
    short* pwT  = ws + 18 * M1;               // 1M
    short* qh   = ws + 19 * M1;               // 4M (z=0 C)
    short* kh   = ws + 23 * M1;               // 4M (z=1 C)
    short* vh   = ws + 27 * M1;               // 4M (z=2 C)
    short* rS   = ws + 31 * M1;               // 2M (z=3 C)  == qh + 3*4M
    short* ao   = xq;                         // alias: xq dead after QKV GEMM

    const dim3 blk(256);

    // ---- prep: convert copies + all transposes, ONE dispatch ----
    CopyDesc cd;
    cd.src[0] = q;      cd.dst[0] = xq;  cd.n[0] = 4 * (int)M1;
    cd.src[1] = k;      cd.dst[1] = xk;  cd.n[1] = 4 * (int)M1;
    cd.src[2] = v;      cd.dst[2] = xv;  cd.n[2] = 4 * (int)M1;
    cd.src[3] = posenc; cd.dst[3] = pe;  cd.n[3] = 2 * (int)M1;
    TransDesc td;
    td.src[0] = q_w;    td.dst[0] = wT;
    td.src[1] = k_w;    td.dst[1] = wT + M1;
    td.src[2] = v_w;    td.dst[2] = wT + 2 * M1;
    td.src[3] = post_w; td.dst[3] = pwT;
    prep_all<<<dim3(9472), blk, 0, stream>>>(cd, td, r_ker, rkT);

    // ---- merged QKV + r projections, XCD-swizzled 1D grid ----
    gemm_bt<<<dim3(896), blk, 0, stream>>>(
        xq, 1024, 4 * M1, wT, 1024, M1, nullptr, k_b, v_b,
        nullptr, 0, qh, 1024, 4 * M1, 1, 1024, 768);

    // ---- attention -> ao bf16 (128 queries/block, 512 blocks) ----
    attn_mfma<<<dim3(512), blk, 0, stream>>>(
        qh, kh, vh, rS, pad, rwb, rrb, ao);

    // ---- post projection + bias + residual -> f32 out, XCD-swizzled ----
    gemm_bt<<<dim3(256), blk, 0, stream>>>(
        ao, 1024, 0, pwT, 1024, 0, post_b, nullptr, nullptr,
        q, 1024, out, 1024, 0, 0, 1024, 1 << 30);

    // ---- LayerNorm in-place ----
    ln_kernel<<<dim3(Bb * Ls), blk, 0, stream>>>(out, ln_g, ln_b);
}

// Round 12
// 268.140 us; speedup vs baseline: 1.0352x; 1.0352x over previous
//
#include <hip/hip_runtime.h>
#include <hip/hip_bf16.h>

// Problem constants
#define Bb 4
#define Ls 1024
#define Dd 1024
#define Nn 16
#define Hh 64
#define Rr 2048

typedef __attribute__((ext_vector_type(8))) short short8;
typedef __attribute__((ext_vector_type(4))) short short4v;
typedef __attribute__((ext_vector_type(4))) float f32x4;

__device__ __forceinline__ float bf2f(short s) {
    union { unsigned u; float f; } c;
    c.u = ((unsigned)(unsigned short)s) << 16;
    return c.f;
}
__device__ __forceinline__ short f2bf(float f) {
    __hip_bfloat16 h = __float2bfloat16(f);
    return *reinterpret_cast<short*>(&h);
}

// async global->LDS, 16B per lane; LDS dest = wave-uniform base + lane*16
__device__ __forceinline__ void gld16(const void* g, void* l) {
    __builtin_amdgcn_global_load_lds(
        (const __attribute__((address_space(1))) unsigned int*)g,
        (__attribute__((address_space(3))) unsigned int*)l, 16, 0, 0);
}

// ---------------------------------------------------------------------------
// Prep (merged): f32->bf16 convert-copies AND all weight transposes in ONE
// dispatch (see r8 notes).
// ---------------------------------------------------------------------------
struct CopyDesc {
    const float* src[4];
    short* dst[4];
    int n[4];
};
struct TransDesc {
    const float* src[4];
    short* dst[4];
};

__global__ __launch_bounds__(256) void prep_all(
    CopyDesc cd, TransDesc td, const float* __restrict__ rker,
    short* __restrict__ rkT)
{
    const int bid = (int)blockIdx.x;
    const int t   = threadIdx.x;

    if (bid < 8192) {
        // ---- convert-copy path ----
        const int z = bid >> 11;
        const int base = ((bid & 2047) * 256 + t) * 8;
        if (base >= cd.n[z]) return;
        const float* s = cd.src[z] + base;
        const float4 a = *(const float4*)s;
        const float4 b = *(const float4*)(s + 4);
        short8 o;
        o[0] = f2bf(a.x); o[1] = f2bf(a.y); o[2] = f2bf(a.z); o[3] = f2bf(a.w);
        o[4] = f2bf(b.x); o[5] = f2bf(b.y); o[6] = f2bf(b.z); o[7] = f2bf(b.w);
        *(short8*)(cd.dst[z] + base) = o;
        return;
    }

    // ---- transpose path ----
    const int tw = bid - 8192;
    const float* in; short* out; int C, r0, c0;
    if (tw < 1024) {
        const int z = tw >> 8, rem = tw & 255;
        in = td.src[z]; out = td.dst[z]; C = 1024;
        r0 = ((rem >> 4) & 15) * 64; c0 = (rem & 15) * 64;
    } else {
        const int s2 = tw - 1024;
        const int sl = s2 >> 4, y = s2 & 15;
        in  = rker + (long)sl * 1024 * 64;
        out = rkT  + (long)sl * 64 * 1024;
        C = 64; r0 = y * 64; c0 = 0;
    }
    __shared__ float T[64][65];
    const int rr = t >> 4, c4 = (t & 15) * 4;
#pragma unroll
    for (int p = 0; p < 4; ++p) {
        const float4 v = *(const float4*)&in[(long)(r0 + p * 16 + rr) * C + c0 + c4];
        T[p * 16 + rr][c4 + 0] = v.x;
        T[p * 16 + rr][c4 + 1] = v.y;
        T[p * 16 + rr][c4 + 2] = v.z;
        T[p * 16 + rr][c4 + 3] = v.w;
    }
    __syncthreads();
#pragma unroll
    for (int p = 0; p < 4; ++p) {
        const int j = p * 16 + (t >> 4);
        const int d4 = (t & 15) * 4;
        short4v o;
#pragma unroll
        for (int u = 0; u < 4; ++u) o[u] = f2bf(T[d4 + u][j]);
        *(short4v*)&out[(long)(c0 + j) * 1024 + r0 + d4] = o;
    }
}

// ---------------------------------------------------------------------------
// MFMA GEMM, templated tile width. BK=64, XOR-swizzled LDS, counted-vmcnt
// 2-phase (r9 notes). BN=128: 4 waves x (64x64), 8 gld16/wave, vmcnt(8) —
// the verified QKV config. BN=64: 4 waves x (32x64), 6 gld16/wave, vmcnt(6),
// grid doubles -> 2 blocks/CU for the post projection (was 1: grid-starved).
// Bijective XCD chunk swizzle. LDS: BN=128 -> 64KB; BN=64 -> 48KB.
// ---------------------------------------------------------------------------
template<int BN>
__global__ __launch_bounds__(256) void gemm_bt(
    const short* __restrict__ A, int lda, long aStride,
    const short* __restrict__ Bt, int ldb, long bStride,
    const float* __restrict__ bias,
    const float* __restrict__ kb, const float* __restrict__ vb,
    const float* __restrict__ residual, int ldr,
    void* __restrict__ Cv, int ldc, long cStride, int out_bf16, int K, int zsplit)
{
    constexpr int NBX   = 1024 / BN;          // col tiles per 1024 cols
    constexpr int WPZ   = 32 * NBX;           // works per full z slice
    constexpr int TM    = (BN == 128) ? 4 : 2;   // wave row-tiles
    constexpr int NWAIT = (BN == 128) ? 8 : 6;   // per-wave gld16 per tile

    const int bid   = (int)blockIdx.x;
    const int chunk = (int)gridDim.x >> 3;
    const int work  = (bid & 7) * chunk + (bid >> 3);
    int z, r;
    if (work < zsplit) { z = work / WPZ; r = work % WPZ; }
    else               { z = 3;          r = work - zsplit; }
    const int by = r / NBX;
    const int bx = r % NBX;

    A  += (long)z * aStride;
    Bt += (long)z * bStride;

    const int row0 = by * 128;
    const int col0 = bx * BN;

    __shared__ short As[2][128 * 64];
    __shared__ short Bs[2][BN * 64];

    const int tid  = threadIdx.x;
    const int w    = tid >> 6;
    const int lane = tid & 63;
    const int quad = lane >> 4;
    const int ln16 = lane & 15;
    const int wr   = (BN == 128) ? (w >> 1) * 64 : w * 32;
    const int wc   = (BN == 128) ? (w & 1) * 64  : 0;

    f32x4 acc[TM][4];
#pragma unroll
    for (int a = 0; a < TM; ++a)
#pragma unroll
        for (int b = 0; b < 4; ++b) acc[a][b] = (f32x4){0.f, 0.f, 0.f, 0.f};

    // staging lane constants (XOR swizzle, attn ks pattern)
    const int srow8 = lane >> 3;            // row within 8-row chunk
    const int sunit = (lane & 7) ^ srow8;   // inverse-swizzled source 16B unit
    const int swz   = ln16 & 7;             // read-side swizzle factor

    // ---- prologue: stage tile 0 ----
    if (BN == 128) {
#pragma unroll
        for (int j = 0; j < 4; ++j) {
            const int c = w * 4 + j;        // 16 chunks of 8 rows
            gld16(A  + (long)(row0 + c * 8 + srow8) * lda + sunit * 8,
                  As[0] + c * 512);
            gld16(Bt + (long)(col0 + c * 8 + srow8) * ldb + sunit * 8,
                  Bs[0] + c * 512);
        }
    } else {
#pragma unroll
        for (int j = 0; j < 4; ++j) {
            const int c = w * 4 + j;        // A: 16 chunks
            gld16(A  + (long)(row0 + c * 8 + srow8) * lda + sunit * 8,
                  As[0] + c * 512);
        }
#pragma unroll
        for (int j = 0; j < 2; ++j) {
            const int c = w * 2 + j;        // B: 8 chunks
            gld16(Bt + (long)(col0 + c * 8 + srow8) * ldb + sunit * 8,
                  Bs[0] + c * 512);
        }
    }

    int cur = 0;
    for (int k0 = 0; k0 < K; k0 += 64) {
        __builtin_amdgcn_s_barrier();       // A: nxt buffer free (all waves)

        if (k0 + 64 < K) {
            const int nxt = cur ^ 1;
            if (BN == 128) {
#pragma unroll
                for (int j = 0; j < 4; ++j) {
                    const int c = w * 4 + j;
                    gld16(A  + (long)(row0 + c * 8 + srow8) * lda + k0 + 64 + sunit * 8,
                          As[nxt] + c * 512);
                    gld16(Bt + (long)(col0 + c * 8 + srow8) * ldb + k0 + 64 + sunit * 8,
                          Bs[nxt] + c * 512);
                }
                asm volatile("s_waitcnt vmcnt(8)" ::: "memory");
            } else {
#pragma unroll
                for (int j = 0; j < 4; ++j) {
                    const int c = w * 4 + j;
                    gld16(A  + (long)(row0 + c * 8 + srow8) * lda + k0 + 64 + sunit * 8,
                          As[nxt] + c * 512);
                }
#pragma unroll
                for (int j = 0; j < 2; ++j) {
                    const int c = w * 2 + j;
                    gld16(Bt + (long)(col0 + c * 8 + srow8) * ldb + k0 + 64 + sunit * 8,
                          Bs[nxt] + c * 512);
                }
                asm volatile("s_waitcnt vmcnt(6)" ::: "memory");
            }
        } else {
            asm volatile("s_waitcnt vmcnt(0)" ::: "memory");   // last tile
        }
        __builtin_amdgcn_s_barrier();       // B: every wave's tile-k data in LDS
        __builtin_amdgcn_sched_barrier(0);

        // ---- compute current tile (next tile's loads still in flight) ----
        short8 af[TM][2], bfr[4][2];
#pragma unroll
        for (int tm = 0; tm < TM; ++tm) {
            const int row = wr + tm * 16 + ln16;
#pragma unroll
            for (int kk = 0; kk < 2; ++kk) {
                const int unit = (kk * 4 + quad) ^ swz;
                af[tm][kk] = *(const short8*)&As[cur][row * 64 + unit * 8];
            }
        }
#pragma unroll
        for (int tn = 0; tn < 4; ++tn) {
            const int row = wc + tn * 16 + ln16;
#pragma unroll
            for (int kk = 0; kk < 2; ++kk) {
                const int unit = (kk * 4 + quad) ^ swz;
                bfr[tn][kk] = *(const short8*)&Bs[cur][row * 64 + unit * 8];
            }
        }
#pragma unroll
        for (int tm = 0; tm < TM; ++tm)
#pragma unroll
            for (int tn = 0; tn < 4; ++tn) {
                acc[tm][tn] = __builtin_amdgcn_mfma_f32_16x16x32_bf16(
                    af[tm][0], bfr[tn][0], acc[tm][tn], 0, 0, 0);
                acc[tm][tn] = __builtin_amdgcn_mfma_f32_16x16x32_bf16(
                    af[tm][1], bfr[tn][1], acc[tm][tn], 0, 0, 0);
            }

        cur ^= 1;
    }

    const float* bz = bias;
    if (z == 1) bz = kb;
    else if (z == 2) bz = vb;

    float bv[4];
#pragma unroll
    for (int tn = 0; tn < 4; ++tn)
        bv[tn] = bz ? bz[col0 + wc + tn * 16 + ln16] : 0.f;

    short* Cb = (short*)Cv + (long)z * cStride;
    float* Cf = (float*)Cv + (long)z * cStride;
#pragma unroll
    for (int tm = 0; tm < TM; ++tm) {
#pragma unroll
        for (int r2 = 0; r2 < 4; ++r2) {
            const long row = row0 + wr + tm * 16 + quad * 4 + r2;
#pragma unroll
            for (int tn = 0; tn < 4; ++tn) {
                const int col = col0 + wc + tn * 16 + ln16;
                float val = acc[tm][tn][r2] + bv[tn];
                if (residual) val += residual[row * (long)ldr + col];
                if (out_bf16) Cb[row * (long)ldc + col] = f2bf(val);
                else          Cf[row * (long)ldc + col] = val;
            }
        }
    }
}

// ---------------------------------------------------------------------------
// MFMA attention (r10 version, unchanged): async prefetch pipeline, ring rS,
// kf/vf hoist, kc-packed P, ballot mask, fixed-max softmax, XCD swizzle.
// LDS 75.5 KB -> 2 blocks/CU.
// ---------------------------------------------------------------------------
#define SCALE_L2E 0.18033688f      // 0.125 * log2(e)

__global__ __launch_bounds__(256, 2) void attn_mfma(
    const short* __restrict__ qh, const short* __restrict__ kh,
    const short* __restrict__ vh, const short* __restrict__ rS,
    const int* __restrict__ padding, const float* __restrict__ rwb,
    const float* __restrict__ rrb, short* __restrict__ ao)
{
    // ---- XCD-aware decode: work = b*128 + n*8 + lt (chunk = 64) ----
    const int bid   = (int)blockIdx.x;
    const int chunk = (int)gridDim.x >> 3;      // 64
    const int work  = (bid & 7) * chunk + (bid >> 3);
    const int lt = work & 7;
    const int n  = (work >> 3) & 15;
    const int b  = work >> 7;

    const int l0 = lt * 128;
    const int tid  = threadIdx.x;
    const int w    = tid >> 6;
    const int lane = tid & 63;
    const int quad = lane >> 4;
    const int ln16 = lane & 15;
    const int qb   = w * 32;          // wave's query base within block

    __shared__ __align__(16) short ks[2][64 * 64]; // DBUF, XOR-swizzled
    __shared__ __align__(16) short rsb[256 * 64];  // RING, XOR-swizzled
    __shared__ __align__(16) short vsT[64][72];    // [d][kc] permuted keys
    __shared__ __align__(16) short psm[4][2][16][72];
    __shared__ unsigned padw[32];                  // pad bitmask, 1024 bits

    // ---- build pad bitmask via wave ballot (16 groups of 64 keys) ----
#pragma unroll
    for (int j = 0; j < 4; ++j) {
        const int g = w + 4 * j;                    // 0..15
        const unsigned long long m =
            __ballot(padding[b * Ls + g * 64 + lane] != 0);
        if (lane == 0) {
            padw[2 * g]     = (unsigned)m;
            padw[2 * g + 1] = (unsigned)(m >> 32);
        }
    }

    // Q fragments (A-layout) for both Q-tiles, biased two ways
    short8 qwf[2][2], qrf[2][2];
#pragma unroll
    for (int qt = 0; qt < 2; ++qt) {
        const long rowoff =
            ((long)(b * Ls + l0 + qb + qt * 16 + ln16)) * (Nn * Hh) + n * Hh;
#pragma unroll
        for (int c = 0; c < 2; ++c) {
            const int kb2 = c * 32 + quad * 8;
            short8 qv = *(const short8*)(qh + rowoff + kb2);
#pragma unroll
            for (int j = 0; j < 8; ++j) {
                float qf = bf2f(qv[j]);
                qwf[qt][c][j] = f2bf(qf + rwb[n * Hh + kb2 + j]);
                qrf[qt][c][j] = f2bf(qf + rrb[n * Hh + kb2 + j]);
            }
        }
    }

    float lsum[2][4];
    f32x4 accO[2][4];
#pragma unroll
    for (int qt = 0; qt < 2; ++qt)
#pragma unroll
        for (int r = 0; r < 4; ++r) {
            lsum[qt][r] = 0.f;
            accO[qt][r] = (f32x4){0.f, 0.f, 0.f, 0.f};
        }

    // staging lane constants (global_load_lds: LDS dest = base + lane*16)
    const int srow8 = lane >> 3;            // row within 8-row chunk
    const int sunit = (lane & 7) ^ srow8;   // inverse-swizzled source 16B unit
    const int swz   = ln16 & 7;             // read-side swizzle factor

    // ---- prologue: K tile 0 -> ks[0]; ring rows [897-l0, +192) ----
#pragma unroll
    for (int j = 0; j < 2; ++j) {
        const int c = w * 2 + j;
        gld16(kh + ((long)(b * Ls + c * 8 + srow8)) * 1024 + n * 64 + sunit * 8,
              ks[0] + c * 512);
    }
    {
        const int base0 = 897 - l0;          // >= 1; max row 1088 (no clamp)
#pragma unroll
        for (int j = 0; j < 6; ++j) {
            const int c = w * 6 + j;         // 0..23
            const int rg = base0 + c * 8 + srow8;
            gld16(rS + (long)rg * 1024 + n * 64 + sunit * 8,
                  rsb + c * 512);
        }
    }

    // V prefetch: thread handles key pair (kp2, kp2+16) -> contiguous kc pair
    const int s5  = tid & 31;
    const int kp2 = (s5 & 15) + ((s5 >> 4) << 5);     // 0..15 or 32..47
    const int kcb = 4 * (s5 & 15) + 2 * (s5 >> 4);    // kc of kp2 (kc+1 = kp2+16)
    const int cq  = (tid >> 5) * 8;                   // d-group base
    short8 va, vb2;
    {
        const short* vp = vh + ((long)(b * Ls + kp2)) * 1024 + n * 64 + cq;
        va  = *(const short8*)vp;
        vb2 = *(const short8*)(vp + 16 * 1024);
    }

    int cur = 0;
    for (int mt = 0; mt < Ls / 64; ++mt) {
        const int m0 = mt * 64;
        // bar A: drains last iteration's loads (landed during compute) and
        // frees vsT / ks[cur^1] / ring tail chunks for overwrite.
        __syncthreads();

        // ---- V^T store from prefetched regs, kc-permuted key pairs ----
#pragma unroll
        for (int u = 0; u < 8; ++u) {
            unsigned pk = ((unsigned)(unsigned short)va[u]) |
                          (((unsigned)(unsigned short)vb2[u]) << 16);
            *(unsigned*)&vsT[cq + u][kcb] = pk;
        }

        // ---- issue mt+1 prefetches (in flight across compute) ----
        {
            const int m1 = m0 + 64;
            const int nxt = cur ^ 1;
            // K tile mt+1 (last iter overruns into adjacent ws; never read)
#pragma unroll
            for (int j = 0; j < 2; ++j) {
                const int c = w * 2 + j;
                gld16(kh + ((long)(b * Ls + m1 + c * 8 + srow8)) * 1024
                         + n * 64 + sunit * 8,
                      ks[nxt] + c * 512);
            }
            // ring tail for window mt+1
            const int tail = 1089 + m0 - l0;            // base(mt) + 192
            const int rcB  = (24 + 8 * mt) & 31;
#pragma unroll
            for (int j = 0; j < 2; ++j) {
                const int jl = w * 2 + j;               // 0..7
                const int rc = (rcB + jl) & 31;         // ring chunk
                int rg = tail + jl * 8 + srow8;
                rg = rg < 2047 ? rg : 2047;             // clamped never gathered
                gld16(rS + (long)rg * 1024 + n * 64 + sunit * 8,
                      rsb + rc * 512);
            }
            // V regs for mt+1 (wraps at end; harmless)
            const int mn = m1 & (Ls - 1);
            const short* vp = vh + ((long)(b * Ls + mn + kp2)) * 1024 + n * 64 + cq;
            va  = *(const short8*)vp;
            vb2 = *(const short8*)(vp + 16 * 1024);
        }

        // vsT ds_writes drained (per-wave), then raw barrier: cross-wave
        // visibility WITHOUT draining the just-issued vmcnt loads.
        asm volatile("s_waitcnt lgkmcnt(0)" ::: "memory");
        __builtin_amdgcn_s_barrier();
        __builtin_amdgcn_sched_barrier(0);

        // ---- Pr B-fragments: 6 union tiles from the ring (shared by qt) ----
        const int rb0 = (96 - qb) + ln16 + m0;   // ring row before &255
        short8 rfU[6][2];
#pragma unroll
        for (int s = 0; s < 6; ++s) {
            const int rr2 = (rb0 + s * 16) & 255;
#pragma unroll
            for (int c2 = 0; c2 < 2; ++c2) {
                const int unit = (c2 * 4 + quad) ^ swz;
                rfU[s][c2] = *(const short8*)&rsb[rr2 * 64 + unit * 8];
            }
        }

        // ---- S = Q K^T (kf hoisted across qt) ----
        __builtin_amdgcn_s_setprio(1);
        f32x4 Sf[2][4];
#pragma unroll
        for (int t = 0; t < 4; ++t) {
            short8 kf0, kf1;
            {
                const int u0 = (0 * 4 + quad) ^ swz;
                const int u1 = (1 * 4 + quad) ^ swz;
                kf0 = *(const short8*)&ks[cur][(t * 16 + ln16) * 64 + u0 * 8];
                kf1 = *(const short8*)&ks[cur][(t * 16 + ln16) * 64 + u1 * 8];
            }
#pragma unroll
            for (int qt = 0; qt < 2; ++qt) {
                f32x4 c = (f32x4){0.f, 0.f, 0.f, 0.f};
                c = __builtin_amdgcn_mfma_f32_16x16x32_bf16(qwf[qt][0], kf0, c, 0, 0, 0);
                c = __builtin_amdgcn_mfma_f32_16x16x32_bf16(qwf[qt][1], kf1, c, 0, 0, 0);
                Sf[qt][t] = c;
            }
        }
        // ---- Pr = Qr · band^T : 5 col-tiles per qt (rfU shared) ----
        f32x4 Prf[2][5];
#pragma unroll
        for (int t = 0; t < 5; ++t) {
#pragma unroll
            for (int qt = 0; qt < 2; ++qt) {
                const int off = qt ? 0 : 1;     // Qt0 -> tiles 1..5, Qt1 -> 0..4
                f32x4 c = (f32x4){0.f, 0.f, 0.f, 0.f};
                c = __builtin_amdgcn_mfma_f32_16x16x32_bf16(qrf[qt][0], rfU[t + off][0], c, 0, 0, 0);
                c = __builtin_amdgcn_mfma_f32_16x16x32_bf16(qrf[qt][1], rfU[t + off][1], c, 0, 0, 0);
                Prf[qt][t] = c;
            }
        }
        __builtin_amdgcn_s_setprio(0);

        // ---- skew gather + fixed-max exp; P stored kc-packed (b64) ----
        const unsigned w0 = padw[(m0 >> 5)];
        const unsigned w1 = padw[(m0 >> 5) + 1];
        const float mbc = -16.0f * 1.44269504f;
        const float mb0 = ((w0 >> ln16) & 1)        ? -1.0e7f : mbc;
        const float mb1 = ((w0 >> (16 + ln16)) & 1) ? -1.0e7f : mbc;
        const float mb2 = ((w1 >> ln16) & 1)        ? -1.0e7f : mbc;
        const float mb3 = ((w1 >> (16 + ln16)) & 1) ? -1.0e7f : mbc;
#pragma unroll
        for (int qt = 0; qt < 2; ++qt) {
#pragma unroll
            for (int r = 0; r < 4; ++r) {
                const int row = quad * 4 + r;
                const int u = ln16 - row + 15;
                const int srcLane = (quad << 4) | (u & 15);
                const float s0 = __shfl(Prf[qt][0][r], srcLane, 64);
                const float s1 = __shfl(Prf[qt][1][r], srcLane, 64);
                const float s2 = __shfl(Prf[qt][2][r], srcLane, 64);
                const float s3 = __shfl(Prf[qt][3][r], srcLane, 64);
                const float s4 = __shfl(Prf[qt][4][r], srcLane, 64);
                const bool hi = (u >= 16);
                const float p0 = __builtin_amdgcn_exp2f(
                    fmaf(Sf[qt][0][r] + (hi ? s1 : s0), SCALE_L2E, mb0));
                const float p1 = __builtin_amdgcn_exp2f(
                    fmaf(Sf[qt][1][r] + (hi ? s2 : s1), SCALE_L2E, mb1));
                const float p2 = __builtin_amdgcn_exp2f(
                    fmaf(Sf[qt][2][r] + (hi ? s3 : s2), SCALE_L2E, mb2));
                const float p3 = __builtin_amdgcn_exp2f(
                    fmaf(Sf[qt][3][r] + (hi ? s4 : s3), SCALE_L2E, mb3));
                lsum[qt][r] += (p0 + p1) + (p2 + p3);
                short4v pk;
                pk[0] = f2bf(p0); pk[1] = f2bf(p1);
                pk[2] = f2bf(p2); pk[3] = f2bf(p3);
                *(short4v*)&psm[w][qt][row][ln16 * 4] = pk;   // kc = ln16*4 + t
            }
        }

        // ---- PV : merged across qt, vf read once per t ----
        short8 pA[2][2];
#pragma unroll
        for (int qt = 0; qt < 2; ++qt)
#pragma unroll
            for (int c2 = 0; c2 < 2; ++c2)
                pA[qt][c2] = *(short8*)&psm[w][qt][ln16][c2 * 32 + quad * 8];
        __builtin_amdgcn_s_setprio(1);
#pragma unroll
        for (int t = 0; t < 4; ++t) {
            short8 vf0 = *(short8*)&vsT[t * 16 + ln16][quad * 8];
            short8 vf1 = *(short8*)&vsT[t * 16 + ln16][32 + quad * 8];
#pragma unroll
            for (int qt = 0; qt < 2; ++qt) {
                f32x4 c = accO[qt][t];
                c = __builtin_amdgcn_mfma_f32_16x16x32_bf16(pA[qt][0], vf0, c, 0, 0, 0);
                c = __builtin_amdgcn_mfma_f32_16x16x32_bf16(pA[qt][1], vf1, c, 0, 0, 0);
                accO[qt][t] = c;
            }
        }
        __builtin_amdgcn_s_setprio(0);

        cur ^= 1;
    }

    // ---- final l reduction (once), then normalize + coalesced store ----
#pragma unroll
    for (int qt = 0; qt < 2; ++qt) {
#pragma unroll
        for (int r = 0; r < 4; ++r) {
            float v = lsum[qt][r];
#pragma unroll
            for (int of = 1; of < 16; of <<= 1) v += __shfl_xor(v, of, 64);
            lsum[qt][r] = 1.f / v;
        }
#pragma unroll
        for (int t = 0; t < 4; ++t)
#pragma unroll
            for (int r = 0; r < 4; ++r)
                psm[w][qt][quad * 4 + r][t * 16 + ln16] =
                    f2bf(accO[qt][t][r] * lsum[qt][(unsigned)r]);
#pragma unroll
        for (int p = 0; p < 2; ++p) {
            const int c = lane + p * 64;
            const int row = c >> 3, cq2 = (c & 7) * 8;
            const long grow = (long)(b * Ls + l0 + qb + qt * 16 + row);
            *(short8*)(ao + grow * 1024 + n * 64 + cq2) = *(short8*)&psm[w][qt][row][cq2];
        }
    }
}

// ---------------------------------------------------------------------------
// LayerNorm in-place over rows of x (4096 x 1024)
// ---------------------------------------------------------------------------
__global__ __launch_bounds__(256) void ln_kernel(
    float* x, const float* __restrict__ g, const float* __restrict__ bb)
{
    const int row = blockIdx.x;
    const int tid = threadIdx.x;
    float4 v = ((const float4*)(x + (long)row * Dd))[tid];
    float s  = v.x + v.y + v.z + v.w;
    float sq = v.x * v.x + v.y * v.y + v.z * v.z + v.w * v.w;
#pragma unroll
    for (int off = 32; off; off >>= 1) {
        s  += __shfl_down(s, off, 64);
        sq += __shfl_down(sq, off, 64);
    }
    __shared__ float ws_s[4], ws_q[4];
    __shared__ float s_mu, s_rstd;
    const int wave = tid >> 6, lane = tid & 63;
    if (lane == 0) { ws_s[wave] = s; ws_q[wave] = sq; }
    __syncthreads();
    if (tid == 0) {
        const float ts = ws_s[0] + ws_s[1] + ws_s[2] + ws_s[3];
        const float tq = ws_q[0] + ws_q[1] + ws_q[2] + ws_q[3];
        const float mu = ts / (float)Dd;
        const float var = tq / (float)Dd - mu * mu;
        s_mu = mu;
        s_rstd = rsqrtf(var + 1e-5f);
    }
    __syncthreads();
    const float mu = s_mu, rstd = s_rstd;
    const float4 gv = ((const float4*)g)[tid];
    const float4 bv = ((const float4*)bb)[tid];
    float4 o;
    o.x = (v.x - mu) * rstd * gv.x + bv.x;
    o.y = (v.y - mu) * rstd * gv.y + bv.y;
    o.z = (v.z - mu) * rstd * gv.z + bv.z;
    o.w = (v.w - mu) * rstd * gv.w + bv.w;
    ((float4*)(x + (long)row * Dd))[tid] = o;
}

// ---------------------------------------------------------------------------
extern "C" void kernel_launch(void* const* d_in, const int* in_sizes, int n_in,
                              void* d_out, int out_size, void* d_ws, size_t ws_size,
                              hipStream_t stream) {
    const float* q      = (const float*)d_in[0];
    const float* k      = (const float*)d_in[1];
    const float* v      = (const float*)d_in[2];
    const float* posenc = (const float*)d_in[3];
    const int*   pad    = (const int*)  d_in[4];
    const float* q_w    = (const float*)d_in[5];
    const float* k_w    = (const float*)d_in[6];
    const float* k_b    = (const float*)d_in[7];
    const float* v_w    = (const float*)d_in[8];
    const float* v_b    = (const float*)d_in[9];
    const float* rwb    = (const float*)d_in[10];
    const float* rrb    = (const float*)d_in[11];
    const float* r_ker  = (const float*)d_in[12];
    const float* post_w = (const float*)d_in[13];
    const float* post_b = (const float*)d_in[14];
    const float* ln_g   = (const float*)d_in[15];
    const float* ln_b   = (const float*)d_in[16];
    float* out = (float*)d_out;

    const long M1 = 1L << 20;                 // 1M elements
    short* ws = (short*)d_ws;
    short* xq   = ws;                         // 4M (z=0 A; aliased by ao later)
    short* xk   = ws + 4 * M1;                // 4M (z=1 A)
    short* xv   = ws + 8 * M1;                // 4M (z=2 A)
    short* pe   = ws + 12 * M1;               // 2M (z=3 A)  == xq + 3*4M
    short* wT   = ws + 14 * M1;               // 3M (qwT,kwT,vwT = z=0..2 B)
    short* rkT  = ws + 17 * M1;               // 1M (z=3 B)  == wT + 3*1M
    short* pwT  = ws + 18 * M1;               // 1M
    short* qh   = ws + 19 * M1;               // 4M (z=0 C)
    short* kh   = ws + 23 * M1;               // 4M (z=1 C)
    short* vh   = ws + 27 * M1;               // 4M (z=2 C)
    short* rS   = ws + 31 * M1;               // 2M (z=3 C)  == qh + 3*4M
    short* ao   = xq;                         // alias: xq dead after QKV GEMM

    const dim3 blk(256);

    // ---- prep: convert copies + all transposes, ONE dispatch ----
    CopyDesc cd;
    cd.src[0] = q;      cd.dst[0] = xq;  cd.n[0] = 4 * (int)M1;
    cd.src[1] = k;      cd.dst[1] = xk;  cd.n[1] = 4 * (int)M1;
    cd.src[2] = v;      cd.dst[2] = xv;  cd.n[2] = 4 * (int)M1;
    cd.src[3] = posenc; cd.dst[3] = pe;  cd.n[3] = 2 * (int)M1;
    TransDesc td;
    td.src[0] = q_w;    td.dst[0] = wT;
    td.src[1] = k_w;    td.dst[1] = wT + M1;
    td.src[2] = v_w;    td.dst[2] = wT + 2 * M1;
    td.src[3] = post_w; td.dst[3] = pwT;
    prep_all<<<dim3(9472), blk, 0, stream>>>(cd, td, r_ker, rkT);

    // ---- merged QKV + r projections, XCD-swizzled 1D grid (BN=128) ----
    gemm_bt<128><<<dim3(896), blk, 0, stream>>>(
        xq, 1024, 4 * M1, wT, 1024, M1, nullptr, k_b, v_b,
        nullptr, 0, qh, 1024, 4 * M1, 1, 1024, 768);

    // ---- attention -> ao bf16 (128 queries/block, 512 blocks) ----
    attn_mfma<<<dim3(512), blk, 0, stream>>>(
        qh, kh, vh, rS, pad, rwb, rrb, ao);

    // ---- post projection + bias + residual -> f32 out (BN=64, 512 blks) ----
    gemm_bt<64><<<dim3(512), blk, 0, stream>>>(
        ao, 1024, 0, pwT, 1024, 0, post_b, nullptr, nullptr,
        q, 1024, out, 1024, 0, 0, 1024, 1 << 30);

    // ---- LayerNorm in-place ----
    ln_kernel<<<dim3(Bb * Ls), blk, 0, stream>>>(out, ln_g, ln_b);
}